// Round 1
// baseline (21039.999 us; speedup 1.0000x reference)
//
#include <hip/hip_runtime.h>
#include <math.h>

#define T_STEPS 1024
#define BPB 8          // batch elements per block
#define FORECAST 30

__device__ __forceinline__ float rcp_fast(float v) {
    return __builtin_amdgcn_rcpf(v);           // v_rcp_f32, ~1 ulp
}
__device__ __forceinline__ float sigm(float v) {
    return rcp_fast(1.0f + __expf(-v));
}
__device__ __forceinline__ float tanh_fast(float v) {
    // tanh(v) = 1 - 2/(1+e^{2v}); inf-safe at both ends
    return 1.0f - 2.0f * rcp_fast(1.0f + __expf(2.0f * v));
}
__device__ __forceinline__ float readlane_f(float v, int lane) {
    return __int_as_float(__builtin_amdgcn_readlane(__float_as_int(v), lane));
}

__global__ __launch_bounds__(256, 2)
void lstm_fused_kernel(const float* __restrict__ x,      // [B, T]
                       const float* __restrict__ W_ih,   // [256]
                       const float* __restrict__ W_hh,   // [256, 64]
                       const float* __restrict__ b_ih,   // [256]
                       const float* __restrict__ b_hh,   // [256]
                       const float* __restrict__ fc_W,   // [30, 64]
                       const float* __restrict__ fc_b,   // [30]
                       float* __restrict__ out)          // [B, 30]
{
    // Wp[k][j] = {W_hh[j][k], W_hh[64+j][k], W_hh[128+j][k], W_hh[192+j][k]}
    __shared__ float4 Wp[64][64];   // 64 KB

    const int tid = threadIdx.x;
    const int j   = tid & 63;       // hidden unit (lane)
    const int bq  = tid >> 6;       // wave id -> batch pair
    const long long bbase = (long long)blockIdx.x * BPB + bq * 2;

    // ---- stage gate-grouped W_hh^T into LDS (one-time) ----
    for (int idx = tid; idx < 64 * 64 * 4; idx += 256) {
        const int k  = idx >> 8;
        const int jj = (idx >> 2) & 63;
        const int g  = idx & 3;
        ((float*)Wp)[idx] = W_hh[(g * 64 + jj) * 64 + k];
    }
    __syncthreads();

    // per-lane input weights / biases for gates {i,f,g,o} of hidden unit j
    const float wi0 = W_ih[j],       wi1 = W_ih[64 + j];
    const float wi2 = W_ih[128 + j], wi3 = W_ih[192 + j];
    const float bb0 = b_ih[j]       + b_hh[j];
    const float bb1 = b_ih[64 + j]  + b_hh[64 + j];
    const float bb2 = b_ih[128 + j] + b_hh[128 + j];
    const float bb3 = b_ih[192 + j] + b_hh[192 + j];

    float hA = 0.f, hB = 0.f, cA = 0.f, cB = 0.f;

    const float4* xA = (const float4*)(x + bbase * T_STEPS);
    const float4* xB = (const float4*)(x + (bbase + 1) * T_STEPS);
    float4 xa = xA[0];
    float4 xb = xB[0];

    for (int t4 = 0; t4 < T_STEPS / 4; ++t4) {
        const int nxt = (t4 + 1 < T_STEPS / 4) ? (t4 + 1) : t4;
        const float4 xa_n = xA[nxt];      // prefetch next chunk
        const float4 xb_n = xB[nxt];
        const float xsA[4] = {xa.x, xa.y, xa.z, xa.w};
        const float xsB[4] = {xb.x, xb.y, xb.z, xb.w};

        #pragma unroll
        for (int tt = 0; tt < 4; ++tt) {
            float aA0 = fmaf(xsA[tt], wi0, bb0);
            float aA1 = fmaf(xsA[tt], wi1, bb1);
            float aA2 = fmaf(xsA[tt], wi2, bb2);
            float aA3 = fmaf(xsA[tt], wi3, bb3);
            float aB0 = fmaf(xsB[tt], wi0, bb0);
            float aB1 = fmaf(xsB[tt], wi1, bb1);
            float aB2 = fmaf(xsB[tt], wi2, bb2);
            float aB3 = fmaf(xsB[tt], wi3, bb3);

            #pragma unroll
            for (int k = 0; k < 64; ++k) {
                const float4 w = Wp[k][j];
                const float sA = readlane_f(hA, k);   // h_prev[k], batch A (SGPR broadcast)
                const float sB = readlane_f(hB, k);   // h_prev[k], batch B
                aA0 = fmaf(sA, w.x, aA0);
                aA1 = fmaf(sA, w.y, aA1);
                aA2 = fmaf(sA, w.z, aA2);
                aA3 = fmaf(sA, w.w, aA3);
                aB0 = fmaf(sB, w.x, aB0);
                aB1 = fmaf(sB, w.y, aB1);
                aB2 = fmaf(sB, w.z, aB2);
                aB3 = fmaf(sB, w.w, aB3);
            }

            // activations + state update (gate order: i, f, g, o)
            const float iA = sigm(aA0), fA = sigm(aA1);
            const float gA = tanh_fast(aA2), oA = sigm(aA3);
            cA = fmaf(fA, cA, iA * gA);
            hA = oA * tanh_fast(cA);

            const float iB = sigm(aB0), fB = sigm(aB1);
            const float gB = tanh_fast(aB2), oB = sigm(aB3);
            cB = fmaf(fB, cB, iB * gB);
            hB = oB * tanh_fast(cB);
        }
        xa = xa_n;
        xb = xb_n;
    }

    // ---- fused FC head: out[b][f] = h_last[b] . fc_W[f] + fc_b[f] ----
    __syncthreads();                       // all waves done reading Wp
    float* hsc = (float*)Wp;               // reuse LDS: hsc[b][j], [8][64]
    hsc[(bq * 2 + 0) * 64 + j] = hA;
    hsc[(bq * 2 + 1) * 64 + j] = hB;
    __syncthreads();

    if (tid < BPB * FORECAST) {            // 240 threads
        const int b = tid / FORECAST;
        const int f = tid % FORECAST;
        float acc = fc_b[f];
        #pragma unroll
        for (int jj = 0; jj < 64; ++jj)
            acc = fmaf(hsc[b * 64 + jj], fc_W[f * 64 + jj], acc);
        out[((long long)blockIdx.x * BPB + b) * FORECAST + f] = acc;
    }
}

extern "C" void kernel_launch(void* const* d_in, const int* in_sizes, int n_in,
                              void* d_out, int out_size, void* d_ws, size_t ws_size,
                              hipStream_t stream) {
    const float* x    = (const float*)d_in[0];
    const float* W_ih = (const float*)d_in[1];
    const float* W_hh = (const float*)d_in[2];
    const float* b_ih = (const float*)d_in[3];
    const float* b_hh = (const float*)d_in[4];
    const float* fc_W = (const float*)d_in[5];
    const float* fc_b = (const float*)d_in[6];
    float* out = (float*)d_out;

    // 4096 batch / 8 per block = 512 blocks (2 blocks/CU), 256 threads (4 waves)
    lstm_fused_kernel<<<512, 256, 0, stream>>>(x, W_ih, W_hh, b_ih, b_hh, fc_W, fc_b, out);
}

// Round 2
// 2715.177 us; speedup vs baseline: 7.7490x; 7.7490x over previous
//
#include <hip/hip_runtime.h>
#include <math.h>

#define T_STEPS 1024
#define C 4            // batch elements per thread (per wave)
#define BPB 16         // batches per block = 4 waves * C
#define FORECAST 30

__device__ __forceinline__ float rcp_fast(float v) {
    return __builtin_amdgcn_rcpf(v);           // v_rcp_f32
}
__device__ __forceinline__ float sigm(float v) {
    return rcp_fast(1.0f + __expf(-v));
}
__device__ __forceinline__ float tanh_fast(float v) {
    // tanh(v) = 1 - 2/(1+e^{2v}); inf-safe at both ends
    return 1.0f - 2.0f * rcp_fast(1.0f + __expf(2.0f * v));
}
__device__ __forceinline__ float readlane_f(float v, int lane) {
    return __int_as_float(__builtin_amdgcn_readlane(__float_as_int(v), lane));
}

__global__ __launch_bounds__(256, 1)
void lstm_fused_kernel(const float* __restrict__ x,      // [B, T]
                       const float* __restrict__ W_ih,   // [256]
                       const float* __restrict__ W_hh,   // [256, 64]
                       const float* __restrict__ b_ih,   // [256]
                       const float* __restrict__ b_hh,   // [256]
                       const float* __restrict__ fc_W,   // [30, 64]
                       const float* __restrict__ fc_b,   // [30]
                       float* __restrict__ out)          // [B, 30]
{
    // Wp[k][j] = {Wi[j][k], Wf[j][k], Wg[j][k], Wo[j][k]}  (gate-grouped W_hh^T)
    __shared__ float4 Wp[64][64];   // 64 KB

    const int tid = threadIdx.x;
    const int j   = tid & 63;       // hidden unit = lane
    const int w   = tid >> 6;       // wave id
    const int bbase = blockIdx.x * BPB + w * C;

    // one-time stage of W_hh^T into LDS
    for (int idx = tid; idx < 64 * 64 * 4; idx += 256) {
        const int k  = idx >> 8;
        const int jj = (idx >> 2) & 63;
        const int g  = idx & 3;
        ((float*)Wp)[idx] = W_hh[(g * 64 + jj) * 64 + k];
    }
    __syncthreads();

    const float wi0 = W_ih[j],       wi1 = W_ih[64 + j];
    const float wi2 = W_ih[128 + j], wi3 = W_ih[192 + j];
    const float bb0 = b_ih[j]       + b_hh[j];
    const float bb1 = b_ih[64 + j]  + b_hh[64 + j];
    const float bb2 = b_ih[128 + j] + b_hh[128 + j];
    const float bb3 = b_ih[192 + j] + b_hh[192 + j];

    float h[C], cst[C];
    const float* xp[C];
    float xc_[C];
    #pragma unroll
    for (int q = 0; q < C; ++q) {
        h[q] = 0.f; cst[q] = 0.f;
        xp[q] = x + (long long)(bbase + q) * T_STEPS;
        xc_[q] = xp[q][0];
    }

    for (int t = 0; t < T_STEPS; ++t) {
        const int tn = (t + 1 < T_STEPS) ? (t + 1) : t;
        float xn_[C];
        #pragma unroll
        for (int q = 0; q < C; ++q) xn_[q] = xp[q][tn];   // prefetch next x

        float a0[C], a1[C], a2[C], a3[C];
        #pragma unroll
        for (int q = 0; q < C; ++q) {
            a0[q] = fmaf(xc_[q], wi0, bb0);
            a1[q] = fmaf(xc_[q], wi1, bb1);
            a2[q] = fmaf(xc_[q], wi2, bb2);
            a3[q] = fmaf(xc_[q], wi3, bb3);
        }

        // h_prev @ W_hh^T : partial unroll keeps code ~2.7 KB (I-cache safe)
        #pragma unroll 16
        for (int k = 0; k < 64; ++k) {
            const float4 wv = Wp[k][j];
            #pragma unroll
            for (int q = 0; q < C; ++q) {
                const float s = readlane_f(h[q], k);   // h_prev[k] broadcast
                a0[q] = fmaf(s, wv.x, a0[q]);
                a1[q] = fmaf(s, wv.y, a1[q]);
                a2[q] = fmaf(s, wv.z, a2[q]);
                a3[q] = fmaf(s, wv.w, a3[q]);
            }
        }

        #pragma unroll
        for (int q = 0; q < C; ++q) {
            const float ig = sigm(a0[q]);
            const float fg = sigm(a1[q]);
            const float gg = tanh_fast(a2[q]);
            const float og = sigm(a3[q]);
            cst[q] = fmaf(fg, cst[q], ig * gg);
            h[q]   = og * tanh_fast(cst[q]);
            xc_[q] = xn_[q];
        }
    }

    // fused FC head
    __syncthreads();
    float* hsc = (float*)Wp;               // reuse LDS: hsc[b][j], [16][64]
    #pragma unroll
    for (int q = 0; q < C; ++q) hsc[(w * C + q) * 64 + j] = h[q];
    __syncthreads();

    for (int o = tid; o < BPB * FORECAST; o += 256) {   // 480 outputs
        const int b = o / FORECAST;
        const int f = o % FORECAST;
        float acc = fc_b[f];
        #pragma unroll
        for (int jj = 0; jj < 64; ++jj)
            acc = fmaf(hsc[b * 64 + jj], fc_W[f * 64 + jj], acc);
        out[((long long)blockIdx.x * BPB + b) * FORECAST + f] = acc;
    }
}

extern "C" void kernel_launch(void* const* d_in, const int* in_sizes, int n_in,
                              void* d_out, int out_size, void* d_ws, size_t ws_size,
                              hipStream_t stream) {
    const float* x    = (const float*)d_in[0];
    const float* W_ih = (const float*)d_in[1];
    const float* W_hh = (const float*)d_in[2];
    const float* b_ih = (const float*)d_in[3];
    const float* b_hh = (const float*)d_in[4];
    const float* fc_W = (const float*)d_in[5];
    const float* fc_b = (const float*)d_in[6];
    float* out = (float*)d_out;

    // 4096 / 16 batches per block = 256 blocks (1/CU), 256 threads (4 waves)
    lstm_fused_kernel<<<256, 256, 0, stream>>>(x, W_ih, W_hh, b_ih, b_hh, fc_W, fc_b, out);
}

// Round 3
// 981.629 us; speedup vs baseline: 21.4338x; 2.7660x over previous
//
#include <hip/hip_runtime.h>
#include <math.h>

#define T_STEPS 1024
#define FORECAST 30

typedef __attribute__((ext_vector_type(8))) short short8v;  // 8 bf16 = 4 VGPRs
typedef __attribute__((ext_vector_type(4))) float f32x4;

__device__ __forceinline__ float rcp_fast(float v){ return __builtin_amdgcn_rcpf(v); }
__device__ __forceinline__ float sigm(float v){ return rcp_fast(1.0f + __expf(-v)); }
__device__ __forceinline__ float tanh_fast(float v){ return 1.0f - 2.0f*rcp_fast(1.0f + __expf(2.0f*v)); }
__device__ __forceinline__ unsigned short f2bf(float f){   // RNE fp32->bf16
    unsigned u = __float_as_uint(f);
    u += 0x7fffu + ((u>>16)&1u);
    return (unsigned short)(u>>16);
}
__device__ __forceinline__ float bf2f(unsigned short s){ return __uint_as_float(((unsigned)s)<<16); }
__device__ __forceinline__ f32x4 mfma16(short8v a, short8v b, f32x4 c){
    return __builtin_amdgcn_mfma_f32_16x16x32_bf16(a, b, c, 0, 0, 0);
}

// Block = 16 batches, 4 waves. Wave w owns gate w (cols [64w,64w+64)).
// A-frag (16x16x32): lane l -> A[m=l&15][k=(l>>4)*8+e]
// B-frag:            lane l -> B[k=(l>>4)*8+e][n=l&15]
// C/D:               lane l -> D[m=(l>>4)*4+reg][n=l&15]   (m89-verified)
__global__ __launch_bounds__(256, 1)
void lstm_mfma_kernel(const float* __restrict__ x,      // [B, T]
                      const float* __restrict__ W_ih,   // [256]
                      const float* __restrict__ W_hh,   // [256, 64]
                      const float* __restrict__ b_ih,   // [256]
                      const float* __restrict__ b_hh,   // [256]
                      const float* __restrict__ fc_W,   // [30, 64]
                      const float* __restrict__ fc_b,   // [30]
                      float* __restrict__ out)          // [B, 30]
{
    __shared__ float gate_lds[4][64][20];                 // [gate][j][batch], pad 16->20
    __shared__ __align__(16) unsigned short hh[16*64];    // h bf16-hi, XOR-swizzled rows
    __shared__ __align__(16) unsigned short hl[16*64];    // h bf16-lo

    const int tid = threadIdx.x;
    const int l   = tid & 63;
    const int w   = tid >> 6;
    const int l15 = l & 15;
    const int l4  = l >> 4;          // 0..3
    const int bb  = blockIdx.x * 16;

    // ---- one-time: W_hh^T bf16 hi/lo fragments into registers ----
    short8v Bhi[4][2], Blo[4][2];
    float wih[4], bia[4];
    #pragma unroll
    for (int tn = 0; tn < 4; ++tn) {
        const int gcol = w*64 + tn*16 + l15;
        wih[tn] = W_ih[gcol];
        bia[tn] = b_ih[gcol] + b_hh[gcol];
        #pragma unroll
        for (int kh = 0; kh < 2; ++kh) {
            const int kb = kh*32 + l4*8;
            const float* wp = W_hh + gcol*64 + kb;   // B[k][n] = W_hh[n][k]
            #pragma unroll
            for (int e = 0; e < 8; ++e) {
                const float v = wp[e];
                const unsigned short hi = f2bf(v);
                const unsigned short lo = f2bf(v - bf2f(hi));
                Bhi[tn][kh][e] = (short)hi;
                Blo[tn][kh][e] = (short)lo;
            }
        }
    }

    // ---- precomputed LDS byte offsets ----
    // A-frag read: row=l15, k-chunk=l4*8; byte = (row*128 + l4*16) ^ ((row&7)<<4); kh flips bit6
    const int abase  = (l15*128 + l4*16) ^ ((l15&7)<<4);
    // gate write: [w][tn*16+l15][l4*4], f32x4; +tn*1280 bytes
    const int gwbase = ((w*64 + l15)*20 + l4*4)*4;
    // gate read: lane=j=l, batches w*4..w*4+3; +g*5120 bytes
    const int grbase = (l*20 + w*4)*4;
    // h write: b=w*4+q, j=l
    int hwoff[4];
    #pragma unroll
    for (int q = 0; q < 4; ++q) {
        const int b = w*4 + q;
        hwoff[q] = (b*128 + l*2) ^ ((b&7)<<4);
    }

    // x: per lane, batches bb + l4*4 + r (16-way lane duplication, cache-served)
    const float* xp[4];
    float xcur[4], xnxt[4];
    #pragma unroll
    for (int r = 0; r < 4; ++r) {
        xp[r]  = x + (long long)(bb + l4*4 + r) * T_STEPS;
        xnxt[r] = xp[r][0];
    }

    float c[4] = {0,0,0,0}, h[4] = {0,0,0,0};
    char* ghp = (char*)hh;
    char* glp = (char*)hl;

    for (int t = 0; t < T_STEPS; ++t) {
        #pragma unroll
        for (int r = 0; r < 4; ++r) xcur[r] = xnxt[r];
        const int tn1 = (t+1 < T_STEPS) ? (t+1) : t;       // prefetch next x
        #pragma unroll
        for (int r = 0; r < 4; ++r) xnxt[r] = xp[r][tn1];

        // acc init = x*W_ih + (b_ih+b_hh), reg r = batch m=l4*4+r
        f32x4 acc[4];
        #pragma unroll
        for (int tn = 0; tn < 4; ++tn) {
            #pragma unroll
            for (int r = 0; r < 4; ++r)
                acc[tn][r] = fmaf(xcur[r], wih[tn], bia[tn]);
        }

        if (t > 0) {   // h==0 at t=0: skip MFMA (and uninitialized-LDS read)
            const short8v ah0 = *(const short8v*)(ghp + abase);
            const short8v ah1 = *(const short8v*)(ghp + (abase ^ 64));
            const short8v al0 = *(const short8v*)(glp + abase);
            const short8v al1 = *(const short8v*)(glp + (abase ^ 64));
            #pragma unroll
            for (int tn = 0; tn < 4; ++tn) {
                acc[tn] = mfma16(ah0, Bhi[tn][0], acc[tn]);
                acc[tn] = mfma16(ah1, Bhi[tn][1], acc[tn]);
                acc[tn] = mfma16(ah0, Blo[tn][0], acc[tn]);
                acc[tn] = mfma16(ah1, Blo[tn][1], acc[tn]);
                acc[tn] = mfma16(al0, Bhi[tn][0], acc[tn]);
                acc[tn] = mfma16(al1, Bhi[tn][1], acc[tn]);
            }
        }

        // activate own gate (wave-uniform branch), write [g][j][b] as f32x4
        if (w == 2) {
            #pragma unroll
            for (int tn = 0; tn < 4; ++tn) {
                f32x4 av;
                #pragma unroll
                for (int r = 0; r < 4; ++r) av[r] = tanh_fast(acc[tn][r]);
                *(f32x4*)(((char*)gate_lds) + gwbase + tn*1280) = av;
            }
        } else {
            #pragma unroll
            for (int tn = 0; tn < 4; ++tn) {
                f32x4 av;
                #pragma unroll
                for (int r = 0; r < 4; ++r) av[r] = sigm(acc[tn][r]);
                *(f32x4*)(((char*)gate_lds) + gwbase + tn*1280) = av;
            }
        }

        __syncthreads();   // gates visible; also protects h-write vs A-reads

        // elementwise: lane = j = l, batches w*4+q
        const f32x4 gi = *(const f32x4*)(((const char*)gate_lds) + grbase + 0*5120);
        const f32x4 gf = *(const f32x4*)(((const char*)gate_lds) + grbase + 1*5120);
        const f32x4 gg = *(const f32x4*)(((const char*)gate_lds) + grbase + 2*5120);
        const f32x4 go = *(const f32x4*)(((const char*)gate_lds) + grbase + 3*5120);
        #pragma unroll
        for (int q = 0; q < 4; ++q) {
            c[q] = fmaf(gf[q], c[q], gi[q]*gg[q]);
            h[q] = go[q] * tanh_fast(c[q]);
            const unsigned short hi = f2bf(h[q]);
            const unsigned short lo = f2bf(h[q] - bf2f(hi));
            *(unsigned short*)(ghp + hwoff[q]) = hi;
            *(unsigned short*)(glp + hwoff[q]) = lo;
        }

        __syncthreads();   // h(t) visible for t+1 A-reads; gate_lds reusable
    }

    // ---- fused FC head ----
    float* hsc = (float*)gate_lds;      // reuse as hsc[16][64]
    #pragma unroll
    for (int q = 0; q < 4; ++q) hsc[(w*4 + q)*64 + l] = h[q];
    __syncthreads();

    for (int o = tid; o < 16*FORECAST; o += 256) {
        const int b = o / FORECAST;
        const int f = o % FORECAST;
        float a = fc_b[f];
        #pragma unroll
        for (int jj = 0; jj < 64; ++jj)
            a = fmaf(hsc[b*64 + jj], fc_W[f*64 + jj], a);
        out[(long long)(bb + b)*FORECAST + f] = a;
    }
}

extern "C" void kernel_launch(void* const* d_in, const int* in_sizes, int n_in,
                              void* d_out, int out_size, void* d_ws, size_t ws_size,
                              hipStream_t stream) {
    const float* x    = (const float*)d_in[0];
    const float* W_ih = (const float*)d_in[1];
    const float* W_hh = (const float*)d_in[2];
    const float* b_ih = (const float*)d_in[3];
    const float* b_hh = (const float*)d_in[4];
    const float* fc_W = (const float*)d_in[5];
    const float* fc_b = (const float*)d_in[6];
    float* out = (float*)d_out;

    // 4096 / 16 batches per block = 256 blocks (1 per CU), 4 waves each
    lstm_mfma_kernel<<<256, 256, 0, stream>>>(x, W_ih, W_hh, b_ih, b_hh, fc_W, fc_b, out);
}

// Round 4
// 727.361 us; speedup vs baseline: 28.9265x; 1.3496x over previous
//
#include <hip/hip_runtime.h>
#include <math.h>

#define T_STEPS 1024
#define FORECAST 30

typedef __attribute__((ext_vector_type(8))) short short8v;  // 8 bf16 = 4 VGPRs
typedef __attribute__((ext_vector_type(4))) float f32x4;

__device__ __forceinline__ float rcp_fast(float v){ return __builtin_amdgcn_rcpf(v); }
__device__ __forceinline__ float exp2_fast(float v){ return __builtin_amdgcn_exp2f(v); }
__device__ __forceinline__ unsigned short f2bf(float f){   // RNE fp32->bf16
    unsigned u = __float_as_uint(f);
    u += 0x7fffu + ((u>>16)&1u);
    return (unsigned short)(u>>16);
}
__device__ __forceinline__ float bf2f(unsigned short s){ return __uint_as_float(((unsigned)s)<<16); }
__device__ __forceinline__ f32x4 mfma16(short8v a, short8v b, f32x4 c){
    return __builtin_amdgcn_mfma_f32_16x16x32_bf16(a, b, c, 0, 0, 0);
}

// Block = 16 batches, 16 waves (1024 thr). Wave w: gate g=w>>2, N-tile tn=w&3.
// A-frag: lane l -> A[m=l&15][k=(l>>4)*8+e]; B-frag: lane l -> B[k=(l>>4)*8+e][n=l&15]
// C/D: lane l -> D[m=(l>>4)*4+reg][n=l&15]    (verified by R3 pass)
__global__ __launch_bounds__(1024, 4)
void lstm_mfma_kernel(const float* __restrict__ x,      // [B, T]
                      const float* __restrict__ W_ih,   // [256]
                      const float* __restrict__ W_hh,   // [256, 64]
                      const float* __restrict__ b_ih,   // [256]
                      const float* __restrict__ b_hh,   // [256]
                      const float* __restrict__ fc_W,   // [30, 64]
                      const float* __restrict__ fc_b,   // [30]
                      float* __restrict__ out)          // [B, 30]
{
    __shared__ float gate_lds[4][16][65];                 // [gate][batch][j], pad 64->65
    __shared__ __align__(16) unsigned short hh[16*64];    // h bf16-hi, XOR-swizzled
    __shared__ __align__(16) unsigned short hl[16*64];    // h bf16-lo
    __shared__ float xs[2][16][65];                       // x chunks: [buf][batch][t&63]

    const int tid = threadIdx.x;
    const int l   = tid & 63;
    const int w   = tid >> 6;       // 0..15
    const int g   = w >> 2;         // gate (i,f,g,o)
    const int tn  = w & 3;          // 16-col tile within gate
    const int l15 = l & 15;
    const int l4  = l >> 4;
    const int bb  = blockIdx.x * 16;

    const float LOG2E = 1.44269504088896f;   // folded into all gate weights

    // ---- one-time: this wave's 16 output cols -> B-frags (bf16 hi/lo) in regs ----
    const int gcol = g*64 + tn*16 + l15;
    const float wih = W_ih[gcol] * LOG2E;
    const float bia = (b_ih[gcol] + b_hh[gcol]) * LOG2E;
    short8v Bhi[2], Blo[2];
    #pragma unroll
    for (int kh = 0; kh < 2; ++kh) {
        const float* wp = W_hh + gcol*64 + kh*32 + l4*8;   // B[k][n] = W_hh[n][k]
        #pragma unroll
        for (int e = 0; e < 8; ++e) {
            const float v = wp[e] * LOG2E;
            const unsigned short hi = f2bf(v);
            const unsigned short lo = f2bf(v - bf2f(hi));
            Bhi[kh][e] = (short)hi;
            Blo[kh][e] = (short)lo;
        }
    }

    // A-frag read: byte = (row*128 + l4*16) ^ ((row&7)<<4), row=l15; kh flips bit 6
    const int abase = (l15*128 + l4*16) ^ ((l15&7)<<4);
    // h write (b=w, j=l): swizzled to match A-reads; w uniform -> contiguous 128B
    const int hwoff = (w*128 + l*2) ^ ((w&7)<<4);
    char* ghp = (char*)hh;
    char* glp = (char*)hl;

    const float* xrow = x + (long long)(bb + w) * T_STEPS;  // wave w stages batch row w

    float cst = 0.f, hst = 0.f;      // state for (batch=w, j=l)

    xs[0][w][l] = xrow[l];           // stage chunk 0 (t = 0..63), coalesced
    __syncthreads();

    for (int t = 0; t < T_STEPS; ++t) {
        const int ch  = (t >> 6) & 1;
        const int tof = t & 63;
        if (tof == 0 && t + 64 < T_STEPS)
            xs[ch ^ 1][w][l] = xrow[t + 64 + l];    // stage next chunk

        // acc init = x*W_ih + bias (xs read: 4-addr broadcast, conflict-free)
        f32x4 acc;
        #pragma unroll
        for (int r = 0; r < 4; ++r)
            acc[r] = fmaf(xs[ch][l4*4 + r][tof], wih, bia);

        if (t > 0) {   // h==0 at t=0
            const short8v ah0 = *(const short8v*)(ghp + abase);
            const short8v ah1 = *(const short8v*)(ghp + (abase ^ 64));
            const short8v al0 = *(const short8v*)(glp + abase);
            const short8v al1 = *(const short8v*)(glp + (abase ^ 64));
            acc = mfma16(ah0, Bhi[0], acc);
            acc = mfma16(ah1, Bhi[1], acc);
            acc = mfma16(ah0, Blo[0], acc);
            acc = mfma16(ah1, Blo[1], acc);
            acc = mfma16(al0, Bhi[0], acc);
            acc = mfma16(al1, Bhi[1], acc);
        }

        // activate own gate (wave-uniform branch); a' = a*log2e already
        if (g == 2) {
            #pragma unroll
            for (int r = 0; r < 4; ++r)   // tanh(a) = 1 - 2/(1+2^(2a'))
                gate_lds[2][l4*4 + r][tn*16 + l15] =
                    1.0f - 2.0f*rcp_fast(1.0f + exp2_fast(2.0f*acc[r]));
        } else {
            #pragma unroll
            for (int r = 0; r < 4; ++r)   // sigm(a) = 1/(1+2^(-a'))
                gate_lds[g][l4*4 + r][tn*16 + l15] =
                    rcp_fast(1.0f + exp2_fast(-acc[r]));
        }

        __syncthreads();

        // elementwise: thread (b=w, j=l) — contiguous gate reads
        const float gi = gate_lds[0][w][l];
        const float gf = gate_lds[1][w][l];
        const float gg = gate_lds[2][w][l];
        const float go = gate_lds[3][w][l];
        cst = fmaf(gf, cst, gi*gg);
        hst = go * (1.0f - 2.0f*rcp_fast(1.0f + exp2_fast(cst * (2.0f*LOG2E))));
        const unsigned short hi_ = f2bf(hst);
        const unsigned short lo_ = f2bf(hst - bf2f(hi_));
        *(unsigned short*)(ghp + hwoff) = hi_;
        *(unsigned short*)(glp + hwoff) = lo_;

        __syncthreads();
    }

    // ---- fused FC head ----
    float* hsc = (float*)gate_lds;      // reuse: hsc[16][64]
    hsc[w*64 + l] = hst;
    __syncthreads();

    if (tid < 16*FORECAST) {
        const int b = tid / FORECAST;
        const int f = tid % FORECAST;
        float a = fc_b[f];
        #pragma unroll
        for (int jj = 0; jj < 64; ++jj)
            a = fmaf(hsc[b*64 + jj], fc_W[f*64 + jj], a);
        out[(long long)(bb + b)*FORECAST + f] = a;
    }
}

extern "C" void kernel_launch(void* const* d_in, const int* in_sizes, int n_in,
                              void* d_out, int out_size, void* d_ws, size_t ws_size,
                              hipStream_t stream) {
    const float* x    = (const float*)d_in[0];
    const float* W_ih = (const float*)d_in[1];
    const float* W_hh = (const float*)d_in[2];
    const float* b_ih = (const float*)d_in[3];
    const float* b_hh = (const float*)d_in[4];
    const float* fc_W = (const float*)d_in[5];
    const float* fc_b = (const float*)d_in[6];
    float* out = (float*)d_out;

    // 4096 / 16 batches per block = 256 blocks (1 per CU), 16 waves = 4/SIMD
    lstm_mfma_kernel<<<256, 1024, 0, stream>>>(x, W_ih, W_hh, b_ih, b_hh, fc_W, fc_b, out);
}

// Round 5
// 649.008 us; speedup vs baseline: 32.4187x; 1.1207x over previous
//
#include <hip/hip_runtime.h>
#include <math.h>

#define T_STEPS 1024
#define FORECAST 30

typedef __attribute__((ext_vector_type(8))) short short8v;  // 8 bf16 = 4 VGPRs
typedef __attribute__((ext_vector_type(4))) float f32x4;

__device__ __forceinline__ float rcp_fast(float v){ return __builtin_amdgcn_rcpf(v); }
__device__ __forceinline__ float exp2_fast(float v){ return __builtin_amdgcn_exp2f(v); }
__device__ __forceinline__ unsigned short f2bf(float f){   // RNE fp32->bf16
    unsigned u = __float_as_uint(f);
    u += 0x7fffu + ((u>>16)&1u);
    return (unsigned short)(u>>16);
}
__device__ __forceinline__ float bf2f(unsigned short s){ return __uint_as_float(((unsigned)s)<<16); }
__device__ __forceinline__ f32x4 mfma16(short8v a, short8v b, f32x4 c){
    return __builtin_amdgcn_mfma_f32_16x16x32_bf16(a, b, c, 0, 0, 0);
}

// Block = 16 batches, 8 waves (512 thr), 256 blocks (1 block/CU, 2 waves/SIMD).
// Weights-as-A: A row rr encodes (j_off = rr>>2, gate = rr&3), B = h^T from LDS.
// D layout (lane l holds rows l4*4+reg, col l15) => lane l holds ALL 4 gates of
// (batch=l15, j=jb+l4) in its 4 acc regs -> elementwise fully in-lane, 1 barrier/step.
__global__ __launch_bounds__(512, 1)
void lstm_mfma_kernel(const float* __restrict__ x,      // [B, T]
                      const float* __restrict__ W_ih,   // [256]
                      const float* __restrict__ W_hh,   // [256, 64]
                      const float* __restrict__ b_ih,   // [256]
                      const float* __restrict__ b_hh,   // [256]
                      const float* __restrict__ fc_W,   // [30, 64]
                      const float* __restrict__ fc_b,   // [30]
                      float* __restrict__ out)          // [B, 30]
{
    __shared__ __align__(16) unsigned short hh[2][16][64];  // h bf16-hi, XOR-swizzled rows
    __shared__ __align__(16) unsigned short hl[2][16][64];  // h bf16-lo
    __shared__ float xs[2][64][16];                         // [chunk][t&63][batch]

    const int tid = threadIdx.x;
    const int l   = tid & 63;
    const int w   = tid >> 6;        // 0..7
    const int l15 = l & 15;
    const int l4  = l >> 4;
    const int bb  = blockIdx.x * 16;
    const int jb0 = w * 8;           // tile 0: j = jb0 + l4
    const int jb1 = w * 8 + 4;       // tile 1

    const float L2E  = 1.44269504088896f;
    const float TL2E = 2.88539008177793f;   // 2*log2(e)

    // ---- one-time: W_hh rows -> A-frags (bf16 hi/lo), gate-scales folded ----
    // Lane supplies A[m=l15][k=l4*8+e]; row l15 -> gate=l15&3, j_off=l15>>2.
    const int   ga   = l15 & 3;
    const int   joff = l15 >> 2;
    const float Srow = (ga == 2) ? TL2E : -L2E;   // tanh rows get +2log2e, sigmoid rows -log2e
    short8v AH[2][2], AL[2][2];                   // [tile][k-chunk]
    {
        const int gc0 = ga*64 + jb0 + joff;
        const int gc1 = ga*64 + jb1 + joff;
        #pragma unroll
        for (int kc = 0; kc < 2; ++kc) {
            const float* p0 = W_hh + gc0*64 + kc*32 + l4*8;
            const float* p1 = W_hh + gc1*64 + kc*32 + l4*8;
            #pragma unroll
            for (int e = 0; e < 8; ++e) {
                const float v0 = p0[e] * Srow;
                const float v1 = p1[e] * Srow;
                const unsigned short u0 = f2bf(v0), u1 = f2bf(v1);
                AH[0][kc][e] = (short)u0;  AL[0][kc][e] = (short)f2bf(v0 - bf2f(u0));
                AH[1][kc][e] = (short)u1;  AL[1][kc][e] = (short)f2bf(v1 - bf2f(u1));
            }
        }
    }

    // wih/bia for the D rows this lane HOLDS: gate=reg, j=jbT+l4
    float wih[2][4], bia[2][4];
    #pragma unroll
    for (int T = 0; T < 2; ++T) {
        const int jb = T ? jb1 : jb0;
        #pragma unroll
        for (int r = 0; r < 4; ++r) {
            const float S  = (r == 2) ? TL2E : -L2E;
            const int   gc = r*64 + jb + l4;
            wih[T][r] = W_ih[gc] * S;
            bia[T][r] = (b_ih[gc] + b_hh[gc]) * S;
        }
    }

    // LDS byte offsets: position (b,j) lives at (b*128 + j*2) ^ ((b&7)<<4)
    const int rbase = (l15*128 + l4*16) ^ ((l15&7)<<4);      // B-frag read (kc=0); kc=1 -> ^64
    const int s0    = (l15*128 + (jb0 + l4)*2) ^ ((l15&7)<<4);
    const int s1    = (l15*128 + (jb1 + l4)*2) ^ ((l15&7)<<4);

    // stage x chunk 0: xs[0][t][b]  (global reads coalesced along t)
    #pragma unroll
    for (int it = 0; it < 2; ++it) {
        const int b  = (tid >> 6) + it*8;
        const int tt = tid & 63;
        xs[0][tt][b] = x[(long long)(bb + b)*T_STEPS + tt];
    }
    __syncthreads();

    float c0 = 0.f, c1 = 0.f, h0 = 0.f, h1 = 0.f;

    for (int t = 0; t < T_STEPS; ++t) {
        const int ch = (t >> 6) & 1;
        if ((t & 63) == 0 && t + 64 < T_STEPS) {   // stage next chunk (safe: prev readers passed barrier)
            #pragma unroll
            for (int it = 0; it < 2; ++it) {
                const int b  = (tid >> 6) + it*8;
                const int tt = tid & 63;
                xs[ch ^ 1][tt][b] = x[(long long)(bb + b)*T_STEPS + t + 64 + tt];
            }
        }
        const float xv = xs[ch][t & 63][l15];      // x[b=l15][t], broadcast read

        // two 3-deep chains per tile (k-halves independent), bias+x in chain A
        f32x4 a0, a1, p0, p1;
        #pragma unroll
        for (int r = 0; r < 4; ++r) {
            a0[r] = fmaf(xv, wih[0][r], bia[0][r]);
            a1[r] = fmaf(xv, wih[1][r], bia[1][r]);
            p0[r] = 0.f; p1[r] = 0.f;
        }

        if (t > 0) {   // h==0 at t=0
            const char* hp = (const char*)hh[(t + 1) & 1];
            const char* lp = (const char*)hl[(t + 1) & 1];
            const short8v bh0 = *(const short8v*)(hp + rbase);
            const short8v bh1 = *(const short8v*)(hp + (rbase ^ 64));
            const short8v bl0 = *(const short8v*)(lp + rbase);
            const short8v bl1 = *(const short8v*)(lp + (rbase ^ 64));
            a0 = mfma16(AH[0][0], bh0, a0);
            a1 = mfma16(AH[1][0], bh0, a1);
            p0 = mfma16(AH[0][1], bh1, p0);
            p1 = mfma16(AH[1][1], bh1, p1);
            a0 = mfma16(AL[0][0], bh0, a0);
            a1 = mfma16(AL[1][0], bh0, a1);
            p0 = mfma16(AL[0][1], bh1, p0);
            p1 = mfma16(AL[1][1], bh1, p1);
            a0 = mfma16(AH[0][0], bl0, a0);
            a1 = mfma16(AH[1][0], bl0, a1);
            p0 = mfma16(AH[0][1], bl1, p0);
            p1 = mfma16(AH[1][1], bl1, p1);
        }

        // in-lane elementwise: all 4 gates live in this lane's acc regs
        unsigned short w_h0, w_l0, w_h1, w_l1;
        {
            const float gi = rcp_fast(1.0f + exp2_fast(a0[0] + p0[0]));
            const float gf = rcp_fast(1.0f + exp2_fast(a0[1] + p0[1]));
            const float gg = fmaf(-2.0f, rcp_fast(1.0f + exp2_fast(a0[2] + p0[2])), 1.0f);
            const float go = rcp_fast(1.0f + exp2_fast(a0[3] + p0[3]));
            c0 = fmaf(gf, c0, gi * gg);
            const float tc = fmaf(-2.0f, rcp_fast(1.0f + exp2_fast(c0 * TL2E)), 1.0f);
            h0 = go * tc;
            w_h0 = f2bf(h0);
            w_l0 = f2bf(h0 - bf2f(w_h0));
        }
        {
            const float gi = rcp_fast(1.0f + exp2_fast(a1[0] + p1[0]));
            const float gf = rcp_fast(1.0f + exp2_fast(a1[1] + p1[1]));
            const float gg = fmaf(-2.0f, rcp_fast(1.0f + exp2_fast(a1[2] + p1[2])), 1.0f);
            const float go = rcp_fast(1.0f + exp2_fast(a1[3] + p1[3]));
            c1 = fmaf(gf, c1, gi * gg);
            const float tc = fmaf(-2.0f, rcp_fast(1.0f + exp2_fast(c1 * TL2E)), 1.0f);
            h1 = go * tc;
            w_h1 = f2bf(h1);
            w_l1 = f2bf(h1 - bf2f(w_h1));
        }

        char* hq = (char*)hh[t & 1];
        char* lq = (char*)hl[t & 1];
        *(unsigned short*)(hq + s0) = w_h0;
        *(unsigned short*)(lq + s0) = w_l0;
        *(unsigned short*)(hq + s1) = w_h1;
        *(unsigned short*)(lq + s1) = w_l1;

        __syncthreads();   // h(t) visible for step t+1
    }

    // ---- fused FC head ----
    float* hsc = (float*)xs;            // reuse: hsc[16][64]
    hsc[l15*64 + jb0 + l4] = h0;
    hsc[l15*64 + jb1 + l4] = h1;
    __syncthreads();

    if (tid < 16*FORECAST) {
        const int b = tid / FORECAST;
        const int f = tid % FORECAST;
        float a = fc_b[f];
        #pragma unroll
        for (int jj = 0; jj < 64; ++jj)
            a = fmaf(hsc[b*64 + jj], fc_W[f*64 + jj], a);
        out[(long long)(bb + b)*FORECAST + f] = a;
    }
}

extern "C" void kernel_launch(void* const* d_in, const int* in_sizes, int n_in,
                              void* d_out, int out_size, void* d_ws, size_t ws_size,
                              hipStream_t stream) {
    const float* x    = (const float*)d_in[0];
    const float* W_ih = (const float*)d_in[1];
    const float* W_hh = (const float*)d_in[2];
    const float* b_ih = (const float*)d_in[3];
    const float* b_hh = (const float*)d_in[4];
    const float* fc_W = (const float*)d_in[5];
    const float* fc_b = (const float*)d_in[6];
    float* out = (float*)d_out;

    // 4096 / 16 batches per block = 256 blocks (1 per CU), 8 waves = 2/SIMD
    lstm_mfma_kernel<<<256, 512, 0, stream>>>(x, W_ih, W_hh, b_ih, b_hh, fc_W, fc_b, out);
}

// Round 6
// 476.904 us; speedup vs baseline: 44.1179x; 1.3609x over previous
//
#include <hip/hip_runtime.h>
#include <math.h>

#define T_STEPS 1024
#define FORECAST 30

typedef __attribute__((ext_vector_type(8))) _Float16 half8;   // 8 fp16 = 4 VGPRs
typedef __attribute__((ext_vector_type(4))) float f32x4;

__device__ __forceinline__ float rcp_fast(float v){ return __builtin_amdgcn_rcpf(v); }
__device__ __forceinline__ float exp2_fast(float v){ return __builtin_amdgcn_exp2f(v); }
__device__ __forceinline__ f32x4 mfma16(half8 a, half8 b, f32x4 c){
    return __builtin_amdgcn_mfma_f32_16x16x32_f16(a, b, c, 0, 0, 0);
}

// Block = 16 batches, 16 waves (1024 thr), 256 blocks (1/CU, 4 waves/SIMD).
// Wave w owns A-tile rows = (j = 4w+joff, gate) packed rr = joff*4+gate.
// fp16 single-plane: gates = A_fp16 x h_fp16 (one product), fp32 accumulate.
// D layout: lane l holds D[m=l4*4+r][n=l15] => (batch=l15, j=4w+l4, gate=r):
// all 4 gates in-lane -> elementwise with zero cross-lane traffic.
__global__ __launch_bounds__(1024, 4)
void lstm_mfma_kernel(const float* __restrict__ x,      // [B, T]
                      const float* __restrict__ W_ih,   // [256]
                      const float* __restrict__ W_hh,   // [256, 64]
                      const float* __restrict__ b_ih,   // [256]
                      const float* __restrict__ b_hh,   // [256]
                      const float* __restrict__ fc_W,   // [30, 64]
                      const float* __restrict__ fc_b,   // [30]
                      float* __restrict__ out)          // [B, 30]
{
    __shared__ __align__(16) _Float16 hs[2][16][64];   // h fp16, XOR-swizzled rows, dbuf
    __shared__ float xs[2][64][16];                    // x chunks: [buf][t&63][batch]

    const int tid = threadIdx.x;
    const int l   = tid & 63;
    const int w   = tid >> 6;        // 0..15
    const int l15 = l & 15;
    const int l4  = l >> 4;
    const int bb  = blockIdx.x * 16;
    const int jl  = w*4 + l4;        // this lane's state j

    const float L2E  = 1.44269504088896f;
    const float TL2E = 2.88539008177793f;   // 2*log2(e)

    // ---- one-time: A-frag (W_hh rows, gate-scale folded, fp16) ----
    // lane supplies A[m=l15][k=l4*8+e]; row m -> gate=m&3, joff=m>>2
    const int   ga   = l15 & 3;
    const int   gc   = ga*64 + w*4 + (l15 >> 2);
    const float Srow = (ga == 2) ? TL2E : -L2E;
    half8 A0, A1;                    // k-chunks 0..31, 32..63
    {
        const float* p = W_hh + gc*64 + l4*8;
        #pragma unroll
        for (int e = 0; e < 8; ++e) {
            A0[e] = (_Float16)(p[e]      * Srow);
            A1[e] = (_Float16)(p[32 + e] * Srow);
        }
    }

    // per-lane x-weights/bias for the gates this lane HOLDS (gate=r, j=jl)
    float wih[4], bia[4];
    #pragma unroll
    for (int r = 0; r < 4; ++r) {
        const float S = (r == 2) ? TL2E : -L2E;
        const int   g = r*64 + jl;
        wih[r] = W_ih[g] * S;
        bia[r] = (b_ih[g] + b_hh[g]) * S;
    }

    // LDS byte offsets: (b,j) -> (b*128 + j*2) ^ ((b&7)<<4)
    const int rbase = (l15*128 + l4*16) ^ ((l15&7)<<4);   // B-frag kc0; kc1 -> ^64
    const int hwoff = (l15*128 + jl*2)  ^ ((l15&7)<<4);   // h write (b=l15, j=jl)
    char* hbase = (char*)hs;

    // stage x chunk 0: thread (b=w, t=l), coalesced along t
    xs[0][l][w] = x[(long long)(bb + w)*T_STEPS + l];
    __syncthreads();

    float cst = 0.f, hv = 0.f;
    float xv = xs[0][0][l15];

    for (int t = 0; t < T_STEPS; ++t) {
        if ((t & 63) == 0 && t + 64 < T_STEPS)   // stage next x chunk
            xs[(((t >> 6) & 1)) ^ 1][l][w] =
                x[(long long)(bb + w)*T_STEPS + t + 64 + l];

        f32x4 acc;
        #pragma unroll
        for (int r = 0; r < 4; ++r) acc[r] = fmaf(xv, wih[r], bia[r]);

        if (t > 0) {   // h==0 at t=0 (also: never read uninit LDS)
            const char* hp = hbase + ((t + 1) & 1) * 2048;
            const half8 b0 = *(const half8*)(hp + rbase);
            const half8 b1 = *(const half8*)(hp + (rbase ^ 64));
            acc = mfma16(A0, b0, acc);
            acc = mfma16(A1, b1, acc);
        }

        // prefetch next x (off the critical path; chunk staged >=1 barrier ago)
        const int t1 = (t + 1 < T_STEPS) ? t + 1 : t;
        const float xvn = xs[(t1 >> 6) & 1][t1 & 63][l15];

        // in-lane elementwise (scales pre-folded: sigmoid -log2e, tanh +2log2e)
        const float gi = rcp_fast(1.0f + exp2_fast(acc[0]));
        const float gf = rcp_fast(1.0f + exp2_fast(acc[1]));
        const float gg = fmaf(-2.0f, rcp_fast(1.0f + exp2_fast(acc[2])), 1.0f);
        const float go = rcp_fast(1.0f + exp2_fast(acc[3]));
        cst = fmaf(gf, cst, gi * gg);
        const float tc = fmaf(-2.0f, rcp_fast(1.0f + exp2_fast(cst * TL2E)), 1.0f);
        hv = go * tc;

        *(_Float16*)(hbase + (t & 1)*2048 + hwoff) = (_Float16)hv;   // h(t) -> dbuf
        xv = xvn;
        __syncthreads();   // h(t) visible for step t+1
    }

    // ---- fused FC head ----
    float* hsc = (float*)xs;            // reuse: hsc[16][64]
    hsc[l15*64 + jl] = hv;              // bijective: (b=l15, j=jl)
    __syncthreads();

    if (tid < 16*FORECAST) {
        const int b = tid / FORECAST;
        const int f = tid % FORECAST;
        float a = fc_b[f];
        #pragma unroll
        for (int jj = 0; jj < 64; ++jj)
            a = fmaf(hsc[b*64 + jj], fc_W[f*64 + jj], a);
        out[(long long)(bb + b)*FORECAST + f] = a;
    }
}

extern "C" void kernel_launch(void* const* d_in, const int* in_sizes, int n_in,
                              void* d_out, int out_size, void* d_ws, size_t ws_size,
                              hipStream_t stream) {
    const float* x    = (const float*)d_in[0];
    const float* W_ih = (const float*)d_in[1];
    const float* W_hh = (const float*)d_in[2];
    const float* b_ih = (const float*)d_in[3];
    const float* b_hh = (const float*)d_in[4];
    const float* fc_W = (const float*)d_in[5];
    const float* fc_b = (const float*)d_in[6];
    float* out = (float*)d_out;

    // 4096 / 16 batches per block = 256 blocks (1 per CU), 16 waves = 4/SIMD
    lstm_mfma_kernel<<<256, 1024, 0, stream>>>(x, W_ih, W_hh, b_ih, b_hh, fc_W, fc_b, out);
}

// Round 7
// 470.793 us; speedup vs baseline: 44.6906x; 1.0130x over previous
//
#include <hip/hip_runtime.h>
#include <math.h>

#define T_STEPS 1024
#define FORECAST 30

typedef __attribute__((ext_vector_type(8))) _Float16 half8;   // 8 fp16 = 4 VGPRs
typedef __attribute__((ext_vector_type(4))) float f32x4;

__device__ __forceinline__ float rcp_fast(float v){ return __builtin_amdgcn_rcpf(v); }
__device__ __forceinline__ float exp2_fast(float v){ return __builtin_amdgcn_exp2f(v); }
__device__ __forceinline__ f32x4 mfma16(half8 a, half8 b, f32x4 c){
    return __builtin_amdgcn_mfma_f32_16x16x32_f16(a, b, c, 0, 0, 0);
}

// Block = 16 batches, 8 waves (512 thr), 256 blocks (1/CU).
// Wave w owns j in [8w, 8w+8) as TWO A-tiles (T=0: j=8w+l4, T=1: j=8w+4+l4).
// B-frags (h) are SHARED by both tiles -> 2 ds_read_b128 per wave-step (was 2
// per tile in the 16-wave layout). Two independent states per lane give 2-way
// ILP through the serial chain (MFMA -> sigma -> c -> tanh -> write).
// D layout: lane l holds D[m=l4*4+r][n=l15] => (batch=l15, j, gate=r) in-lane.
__global__ __launch_bounds__(512, 1)
void lstm_mfma_kernel(const float* __restrict__ x,      // [B, T]
                      const float* __restrict__ W_ih,   // [256]
                      const float* __restrict__ W_hh,   // [256, 64]
                      const float* __restrict__ b_ih,   // [256]
                      const float* __restrict__ b_hh,   // [256]
                      const float* __restrict__ fc_W,   // [30, 64]
                      const float* __restrict__ fc_b,   // [30]
                      float* __restrict__ out)          // [B, 30]
{
    __shared__ __align__(16) _Float16 hs[2][16][64];   // h fp16, swizzled, dbuf (4 KB)
    __shared__ float xs[2][64][16];                    // x chunks [buf][t&63][batch] (8 KB)

    const int tid = threadIdx.x;
    const int l   = tid & 63;
    const int w   = tid >> 6;        // 0..7
    const int l15 = l & 15;
    const int l4  = l >> 4;
    const int bb  = blockIdx.x * 16;

    const float L2E  = 1.44269504088896f;
    const float TL2E = 2.88539008177793f;   // 2*log2(e)

    // ---- one-time: A-frags (W_hh rows, gate-scale folded, fp16), 2 tiles ----
    // lane supplies A[m=l15][k=l4*8+e]; row m -> gate=m&3, joff=m>>2
    const int   ga   = l15 & 3;
    const float Srow = (ga == 2) ? TL2E : -L2E;
    half8 A[2][2];                   // [tile][k-chunk]
    #pragma unroll
    for (int T = 0; T < 2; ++T) {
        const int gc = ga*64 + w*8 + T*4 + (l15 >> 2);
        #pragma unroll
        for (int kc = 0; kc < 2; ++kc) {
            const float* p = W_hh + gc*64 + kc*32 + l4*8;
            #pragma unroll
            for (int e = 0; e < 8; ++e)
                A[T][kc][e] = (_Float16)(p[e] * Srow);
        }
    }

    // per-lane x-weights/bias for the 2 states this lane HOLDS (gate=r, j=jT)
    const int j0 = w*8 + l4;
    const int j1 = w*8 + 4 + l4;
    float wih[2][4], bia[2][4];
    #pragma unroll
    for (int T = 0; T < 2; ++T) {
        const int jT = T ? j1 : j0;
        #pragma unroll
        for (int r = 0; r < 4; ++r) {
            const float S = (r == 2) ? TL2E : -L2E;
            const int   g = r*64 + jT;
            wih[T][r] = W_ih[g] * S;
            bia[T][r] = (b_ih[g] + b_hh[g]) * S;
        }
    }

    // LDS byte offsets: (b,j) -> (b*128 + j*2) ^ ((b&7)<<4)
    const int rbase = (l15*128 + l4*16) ^ ((l15&7)<<4);   // B-frag kc0; kc1 -> ^64
    const int hw0   = (l15*128 + j0*2)  ^ ((l15&7)<<4);
    const int hw1   = (l15*128 + j1*2)  ^ ((l15&7)<<4);
    char* hbase = (char*)hs;

    // stage x chunk 0: thread (w,l) stages t=l for b=w and b=w+8 (coalesced in t)
    #pragma unroll
    for (int it = 0; it < 2; ++it) {
        const int b = w + it*8;
        xs[0][l][b] = x[(long long)(bb + b)*T_STEPS + l];
    }
    __syncthreads();

    float c0 = 0.f, c1 = 0.f, h0 = 0.f, h1 = 0.f;
    float xv = xs[0][0][l15];

    for (int t = 0; t < T_STEPS; ++t) {
        if ((t & 63) == 0 && t + 64 < T_STEPS) {   // stage next x chunk
            #pragma unroll
            for (int it = 0; it < 2; ++it) {
                const int b = w + it*8;
                xs[(((t >> 6) & 1)) ^ 1][l][b] =
                    x[(long long)(bb + b)*T_STEPS + t + 64 + l];
            }
        }

        // independent accumulators per k-half (no serial acc dependency)
        f32x4 aA, aB, pA, pB;
        #pragma unroll
        for (int r = 0; r < 4; ++r) {
            aA[r] = fmaf(xv, wih[0][r], bia[0][r]);
            aB[r] = fmaf(xv, wih[1][r], bia[1][r]);
            pA[r] = 0.f; pB[r] = 0.f;
        }

        if (t > 0) {   // h==0 at t=0
            const char* hp = hbase + ((t + 1) & 1) * 2048;
            const half8 b0 = *(const half8*)(hp + rbase);          // shared by both tiles
            const half8 b1 = *(const half8*)(hp + (rbase ^ 64));
            aA = mfma16(A[0][0], b0, aA);
            aB = mfma16(A[1][0], b0, aB);
            pA = mfma16(A[0][1], b1, pA);
            pB = mfma16(A[1][1], b1, pB);
        }

        // prefetch next x (chunk staged >=1 barrier ago)
        const int t1 = (t + 1 < T_STEPS) ? t + 1 : t;
        const float xvn = xs[(t1 >> 6) & 1][t1 & 63][l15];

        // in-lane elementwise, 2 independent states (compiler interleaves)
        {
            const float gi = rcp_fast(1.0f + exp2_fast(aA[0] + pA[0]));
            const float gf = rcp_fast(1.0f + exp2_fast(aA[1] + pA[1]));
            const float gg = fmaf(-2.0f, rcp_fast(1.0f + exp2_fast(aA[2] + pA[2])), 1.0f);
            const float go = rcp_fast(1.0f + exp2_fast(aA[3] + pA[3]));
            c0 = fmaf(gf, c0, gi * gg);
            const float tc = fmaf(-2.0f, rcp_fast(1.0f + exp2_fast(c0 * TL2E)), 1.0f);
            h0 = go * tc;
        }
        {
            const float gi = rcp_fast(1.0f + exp2_fast(aB[0] + pB[0]));
            const float gf = rcp_fast(1.0f + exp2_fast(aB[1] + pB[1]));
            const float gg = fmaf(-2.0f, rcp_fast(1.0f + exp2_fast(aB[2] + pB[2])), 1.0f);
            const float go = rcp_fast(1.0f + exp2_fast(aB[3] + pB[3]));
            c1 = fmaf(gf, c1, gi * gg);
            const float tc = fmaf(-2.0f, rcp_fast(1.0f + exp2_fast(c1 * TL2E)), 1.0f);
            h1 = go * tc;
        }

        char* hq = hbase + (t & 1) * 2048;
        *(_Float16*)(hq + hw0) = (_Float16)h0;
        *(_Float16*)(hq + hw1) = (_Float16)h1;
        xv = xvn;
        __syncthreads();   // h(t) visible for step t+1
    }

    // ---- fused FC head ----
    float* hsc = (float*)xs;            // reuse: hsc[16][64]
    hsc[l15*64 + j0] = h0;
    hsc[l15*64 + j1] = h1;
    __syncthreads();

    if (tid < 16*FORECAST) {
        const int b = tid / FORECAST;
        const int f = tid % FORECAST;
        float a = fc_b[f];
        #pragma unroll
        for (int jj = 0; jj < 64; ++jj)
            a = fmaf(hsc[b*64 + jj], fc_W[f*64 + jj], a);
        out[(long long)(bb + b)*FORECAST + f] = a;
    }
}

extern "C" void kernel_launch(void* const* d_in, const int* in_sizes, int n_in,
                              void* d_out, int out_size, void* d_ws, size_t ws_size,
                              hipStream_t stream) {
    const float* x    = (const float*)d_in[0];
    const float* W_ih = (const float*)d_in[1];
    const float* W_hh = (const float*)d_in[2];
    const float* b_ih = (const float*)d_in[3];
    const float* b_hh = (const float*)d_in[4];
    const float* fc_W = (const float*)d_in[5];
    const float* fc_b = (const float*)d_in[6];
    float* out = (float*)d_out;

    // 4096 / 16 batches per block = 256 blocks (1 per CU), 8 waves
    lstm_mfma_kernel<<<256, 512, 0, stream>>>(x, W_ih, W_hh, b_ih, b_hh, fc_W, fc_b, out);
}

// Round 8
// 450.357 us; speedup vs baseline: 46.7185x; 1.0454x over previous
//
#include <hip/hip_runtime.h>
#include <math.h>

#define T_STEPS 1024
#define FORECAST 30

typedef __attribute__((ext_vector_type(8))) _Float16 half8;   // 8 fp16 = 4 VGPRs
typedef __attribute__((ext_vector_type(4))) _Float16 half4;   // 4 fp16 = 2 VGPRs
typedef __attribute__((ext_vector_type(4))) float f32x4;

__device__ __forceinline__ float rcp_fast(float v){ return __builtin_amdgcn_rcpf(v); }
__device__ __forceinline__ float exp2_fast(float v){ return __builtin_amdgcn_exp2f(v); }
__device__ __forceinline__ f32x4 mfma16(half8 a, half8 b, f32x4 c){
    return __builtin_amdgcn_mfma_f32_16x16x32_f16(a, b, c, 0, 0, 0);
}

// Block = 16 batches, 4 waves (256 thr), 256 blocks (1/CU, 1 wave/SIMD).
// Wave w owns j in [16w,16w+16) as FOUR A-tiles; B-frags (h) shared by all 4
// -> only 2 ds_read_b128 per wave-step (8/CU). 4 independent states/lane give
// 4-way ILP through the serial chain. h stored j-PERMUTED (p = w*16+l4*4+T) so
// each lane's 4 h-values are contiguous -> single ds_write_b64; permutation is
// baked into the A-fragments at build time (j_of_p).
// Elementwise uses common-denominator form: 7 trans + ~16 VALU per state.
__global__ __launch_bounds__(256, 1)
void lstm_mfma_kernel(const float* __restrict__ x,      // [B, T]
                      const float* __restrict__ W_ih,   // [256]
                      const float* __restrict__ W_hh,   // [256, 64]
                      const float* __restrict__ b_ih,   // [256]
                      const float* __restrict__ b_hh,   // [256]
                      const float* __restrict__ fc_W,   // [30, 64]
                      const float* __restrict__ fc_b,   // [30]
                      float* __restrict__ out)          // [B, 30]
{
    __shared__ __align__(16) _Float16 hs[2][16][64];   // h fp16, swizzled, dbuf (4 KB)
    __shared__ float xs[2][64][16];                    // x chunks [buf][t&63][batch] (8 KB)

    const int tid = threadIdx.x;
    const int l   = tid & 63;
    const int w   = tid >> 6;        // 0..3
    const int l15 = l & 15;
    const int l4  = l >> 4;
    const int bb  = blockIdx.x * 16;

    const float L2E  = 1.44269504088896f;
    const float TL2E = 2.88539008177793f;   // 2*log2(e)

    // ---- one-time: A-frags (4 tiles), gate-scales folded, j-perm baked ----
    // lane supplies A[m=l15][k'=kc*32+l4*8+e]; row m -> gate=m&3, joff=m>>2.
    // storage slot p holds h[j_of_p(p)], j_of_p(p) = (p&~15) + (p&3)*4 + ((p>>2)&3)
    const int   ga   = l15 & 3;
    const float Srow = (ga == 2) ? TL2E : -L2E;   // tanh row +2log2e, sigmoid -log2e
    half8 A[4][2];                   // [tile][k-chunk]
    #pragma unroll
    for (int T = 0; T < 4; ++T) {
        const int gc = ga*64 + w*16 + T*4 + (l15 >> 2);   // W_hh row (gate,j_out)
        #pragma unroll
        for (int kc = 0; kc < 2; ++kc) {
            #pragma unroll
            for (int e = 0; e < 8; ++e) {
                const int p   = kc*32 + l4*8 + e;
                const int jin = (p & ~15) + ((p & 3) << 2) + ((p >> 2) & 3);
                A[T][kc][e] = (_Float16)(W_hh[gc*64 + jin] * Srow);
            }
        }
    }

    // per-lane x-weights/bias for the 4 states this lane HOLDS (gate=r, j=jT)
    float wih[4][4], bia[4][4];
    #pragma unroll
    for (int T = 0; T < 4; ++T) {
        const int jT = w*16 + T*4 + l4;
        #pragma unroll
        for (int r = 0; r < 4; ++r) {
            const float S = (r == 2) ? TL2E : -L2E;
            const int   g = r*64 + jT;
            wih[T][r] = W_ih[g] * S;
            bia[T][r] = (b_ih[g] + b_hh[g]) * S;
        }
    }

    // LDS byte offsets (swizzle: ^((b&7)<<4)):
    const int rbase = (l15*128 + l4*16) ^ ((l15&7)<<4);         // B-frag kc0; kc1 -> ^64
    const int hwoff = (l15*128 + w*32 + l4*8) ^ ((l15&7)<<4);   // b64 write, p0 = w*16+l4*4
    char* hbase = (char*)hs;

    // stage x chunk 0: thread (w,l) stages t=l for batches w*4..w*4+3 (coalesced in t)
    #pragma unroll
    for (int it = 0; it < 4; ++it) {
        const int b = w*4 + it;
        xs[0][l][b] = x[(long long)(bb + b)*T_STEPS + l];
    }
    __syncthreads();

    float c[4] = {0,0,0,0}, h[4] = {0,0,0,0};
    float xv = xs[0][0][l15];

    for (int t = 0; t < T_STEPS; ++t) {
        if ((t & 63) == 0 && t + 64 < T_STEPS) {   // stage next x chunk
            #pragma unroll
            for (int it = 0; it < 4; ++it) {
                const int b = w*4 + it;
                xs[(((t >> 6) & 1)) ^ 1][l][b] =
                    x[(long long)(bb + b)*T_STEPS + t + 64 + l];
            }
        }

        f32x4 acc[4];
        #pragma unroll
        for (int T = 0; T < 4; ++T)
            #pragma unroll
            for (int r = 0; r < 4; ++r)
                acc[T][r] = fmaf(xv, wih[T][r], bia[T][r]);

        if (t > 0) {   // h==0 at t=0
            const char* hp = hbase + ((t + 1) & 1) * 2048;
            const half8 b0 = *(const half8*)(hp + rbase);        // shared by all 4 tiles
            const half8 b1 = *(const half8*)(hp + (rbase ^ 64));
            #pragma unroll
            for (int T = 0; T < 4; ++T) {
                acc[T] = mfma16(A[T][0], b0, acc[T]);
                acc[T] = mfma16(A[T][1], b1, acc[T]);
            }
        }

        // prefetch next x (chunk staged >=1 barrier ago)
        const int t1 = (t + 1 < T_STEPS) ? t + 1 : t;
        const float xvn = xs[(t1 >> 6) & 1][t1 & 63][l15];

        // in-lane elementwise, common-denominator form, 4 independent states:
        // i=1/u, f=1/v, g=(s-2)/s, o=1/(1+Do); c' = (c*u*s + v*(s-2))/(u*v*s)
        // h = o*tanh(c') = (T-1)/((1+Do)*(T+1)), T = 2^min(c'*2log2e, 80)
        half4 hv;
        #pragma unroll
        for (int T = 0; T < 4; ++T) {
            const float A_ = exp2_fast(acc[T][0]);
            const float B_ = exp2_fast(acc[T][1]);
            const float C2 = exp2_fast(acc[T][2]);
            const float Do = exp2_fast(acc[T][3]);
            const float u  = 1.0f + A_;
            const float v  = 1.0f + B_;
            const float s  = 1.0f + C2;
            const float m  = s - 2.0f;
            const float us = u * s;
            const float N  = fmaf(c[T], us, v * m);
            const float cn = N * rcp_fast(us * v);
            c[T] = cn;
            const float Tt = exp2_fast(fminf(cn * TL2E, 80.0f));
            const float hn = (Tt - 1.0f) * rcp_fast((1.0f + Do) * (Tt + 1.0f));
            h[T] = hn;
            hv[T] = (_Float16)hn;
        }

        // single b64 store: slots p0..p0+3 (j-permuted layout)
        *(half4*)(hbase + (t & 1)*2048 + hwoff) = hv;
        xv = xvn;
        __syncthreads();   // h(t) visible for step t+1
    }

    // ---- fused FC head ----
    float* hsc = (float*)xs;            // reuse: hsc[16][64] (actual j indexing)
    #pragma unroll
    for (int T = 0; T < 4; ++T)
        hsc[l15*64 + w*16 + T*4 + l4] = h[T];
    __syncthreads();

    for (int o = tid; o < 16*FORECAST; o += 256) {
        const int b = o / FORECAST;
        const int f = o % FORECAST;
        float a = fc_b[f];
        #pragma unroll
        for (int jj = 0; jj < 64; ++jj)
            a = fmaf(hsc[b*64 + jj], fc_W[f*64 + jj], a);
        out[(long long)(bb + b)*FORECAST + f] = a;
    }
}

extern "C" void kernel_launch(void* const* d_in, const int* in_sizes, int n_in,
                              void* d_out, int out_size, void* d_ws, size_t ws_size,
                              hipStream_t stream) {
    const float* x    = (const float*)d_in[0];
    const float* W_ih = (const float*)d_in[1];
    const float* W_hh = (const float*)d_in[2];
    const float* b_ih = (const float*)d_in[3];
    const float* b_hh = (const float*)d_in[4];
    const float* fc_W = (const float*)d_in[5];
    const float* fc_b = (const float*)d_in[6];
    float* out = (float*)d_out;

    // 4096 / 16 batches per block = 256 blocks (1 per CU), 4 waves (1/SIMD)
    lstm_mfma_kernel<<<256, 256, 0, stream>>>(x, W_ih, W_hh, b_ih, b_hh, fc_W, fc_b, out);
}

// Round 9
// 396.635 us; speedup vs baseline: 53.0462x; 1.1354x over previous
//
#include <hip/hip_runtime.h>
#include <math.h>

#define T_STEPS 1024
#define FORECAST 30

typedef __attribute__((ext_vector_type(8))) _Float16 half8;    // 8 fp16 = 4 VGPRs
typedef __attribute__((ext_vector_type(2))) _Float16 half2v;   // 2 fp16 = 1 VGPR
typedef __attribute__((ext_vector_type(4))) float f32x4;
typedef __attribute__((ext_vector_type(2))) float f32x2;       // -> v_pk_*_f32

__device__ __forceinline__ float rcp_fast(float v){ return __builtin_amdgcn_rcpf(v); }
__device__ __forceinline__ float exp2_fast(float v){ return __builtin_amdgcn_exp2f(v); }
__device__ __forceinline__ f32x4 mfma16(half8 a, half8 b, f32x4 c){
    return __builtin_amdgcn_mfma_f32_16x16x32_f16(a, b, c, 0, 0, 0);
}

// Block = 16 batches, 8 waves (512 thr), 256 blocks (1/CU, 2 waves/SIMD).
// Wave w owns j in [8w,8w+8) as TWO A-tiles (T: j=8w+T*4+l4); B-frags (h)
// shared by both -> 2 ds_read_b128/wave-step. 2 waves/SIMD give a second
// instruction stream to hide ds_read + trans latency (R8's 1 wave/SIMD
// exposed ~42% stall). Elementwise = common-denominator form (7 trans/state),
// both states packed as f32x2 -> v_pk_{add,mul,fma}_f32.
// h stored j-permuted: slot p = w*8 + l4*2 + T  <->  j = (p&~7)+(p&1)*4+((p&7)>>1)
// (permutation baked into A-frag k-dim) -> one b32 h-write per lane.
// D layout: lane l holds D[m=l4*4+r][n=l15] => (batch=l15, j, gate=r) in-lane.
__global__ __launch_bounds__(512, 1)
void lstm_mfma_kernel(const float* __restrict__ x,      // [B, T]
                      const float* __restrict__ W_ih,   // [256]
                      const float* __restrict__ W_hh,   // [256, 64]
                      const float* __restrict__ b_ih,   // [256]
                      const float* __restrict__ b_hh,   // [256]
                      const float* __restrict__ fc_W,   // [30, 64]
                      const float* __restrict__ fc_b,   // [30]
                      float* __restrict__ out)          // [B, 30]
{
    __shared__ __align__(16) _Float16 hs[2][16][64];   // h fp16, swizzled slots, dbuf
    __shared__ float xs[2][64][16];                    // x chunks [buf][t&63][batch]

    const int tid = threadIdx.x;
    const int l   = tid & 63;
    const int w   = tid >> 6;        // 0..7
    const int l15 = l & 15;
    const int l4  = l >> 4;
    const int bb  = blockIdx.x * 16;

    const float L2E  = 1.44269504088896f;
    const float TL2E = 2.88539008177793f;   // 2*log2(e)

    // ---- one-time: A-frags (2 tiles), gate-scales folded, j-perm baked ----
    // lane supplies A[m=l15][k=kc*32+l4*8+e]; row m -> gate=m&3, joff=m>>2
    const int   ga   = l15 & 3;
    const float Srow = (ga == 2) ? TL2E : -L2E;   // tanh rows +2log2e, sigmoid -log2e
    half8 A[2][2];                   // [tile][k-chunk]
    #pragma unroll
    for (int T = 0; T < 2; ++T) {
        const int gc = ga*64 + w*8 + T*4 + (l15 >> 2);   // W_hh row (gate, j_out)
        #pragma unroll
        for (int kc = 0; kc < 2; ++kc) {
            #pragma unroll
            for (int e = 0; e < 8; ++e) {
                const int p   = kc*32 + l4*8 + e;        // B slot
                const int jin = (p & ~7) + ((p & 1) << 2) + ((p & 7) >> 1);
                A[T][kc][e] = (_Float16)(W_hh[gc*64 + jin] * Srow);
            }
        }
    }

    // per-lane x-weights/bias for the 2 states this lane HOLDS (gate=r, j=jT)
    float wih[2][4], bia[2][4];
    #pragma unroll
    for (int T = 0; T < 2; ++T) {
        const int jT = w*8 + T*4 + l4;
        #pragma unroll
        for (int r = 0; r < 4; ++r) {
            const float S = (r == 2) ? TL2E : -L2E;
            const int   g = r*64 + jT;
            wih[T][r] = W_ih[g] * S;
            bia[T][r] = (b_ih[g] + b_hh[g]) * S;
        }
    }

    // LDS byte offsets (swizzle ^((b&7)<<4)):
    const int rbase = (l15*128 + l4*16) ^ ((l15&7)<<4);           // B-frag kc0; kc1 -> ^64
    const int hwoff = (l15*128 + w*16 + l4*4) ^ ((l15&7)<<4);     // b32 write, slots p0,p0+1
    char* hbase = (char*)hs;

    // stage x chunk 0: thread (w,l) stages t=l for batches w*2, w*2+1
    #pragma unroll
    for (int it = 0; it < 2; ++it) {
        const int b = w*2 + it;
        xs[0][l][b] = x[(long long)(bb + b)*T_STEPS + l];
    }
    __syncthreads();

    f32x2 cc = {0.f, 0.f}, hh01 = {0.f, 0.f};
    float xv = xs[0][0][l15];

    for (int t = 0; t < T_STEPS; ++t) {
        // B-frag reads first (longest-latency consumer chain)
        half8 b0, b1;
        if (t > 0) {
            const char* hp = hbase + ((t + 1) & 1) * 2048;
            b0 = *(const half8*)(hp + rbase);
            b1 = *(const half8*)(hp + (rbase ^ 64));
        }

        if ((t & 63) == 0 && t + 64 < T_STEPS) {   // stage next x chunk
            #pragma unroll
            for (int it = 0; it < 2; ++it) {
                const int b = w*2 + it;
                xs[(((t >> 6) & 1)) ^ 1][l][b] =
                    x[(long long)(bb + b)*T_STEPS + t + 64 + l];
            }
        }

        f32x4 acc0, acc1;
        #pragma unroll
        for (int r = 0; r < 4; ++r) {
            acc0[r] = fmaf(xv, wih[0][r], bia[0][r]);
            acc1[r] = fmaf(xv, wih[1][r], bia[1][r]);
        }

        if (t > 0) {   // h==0 at t=0
            acc0 = mfma16(A[0][0], b0, acc0);
            acc1 = mfma16(A[1][0], b0, acc1);
            acc0 = mfma16(A[0][1], b1, acc0);
            acc1 = mfma16(A[1][1], b1, acc1);
        }

        // prefetch next x (chunk staged >=1 barrier ago)
        const int t1 = (t + 1 < T_STEPS) ? t + 1 : t;
        const float xvn = xs[(t1 >> 6) & 1][t1 & 63][l15];

        // packed elementwise (states T=0,1 in lanes of f32x2 -> v_pk_*):
        // i=1/u, f=1/v, g=(s-2)/s, o=1/(1+Do); c' = (c*us + v*m)/(us*v)
        // h = (Tt-1)/((1+Do)(Tt+1)), Tt = 2^min(c'*2log2e, 80)
        f32x2 eI, eF, eG, eO;
        eI[0] = exp2_fast(acc0[0]); eI[1] = exp2_fast(acc1[0]);
        eF[0] = exp2_fast(acc0[1]); eF[1] = exp2_fast(acc1[1]);
        eG[0] = exp2_fast(acc0[2]); eG[1] = exp2_fast(acc1[2]);
        eO[0] = exp2_fast(acc0[3]); eO[1] = exp2_fast(acc1[3]);
        const f32x2 u  = eI + 1.0f;
        const f32x2 v  = eF + 1.0f;
        const f32x2 s  = eG + 1.0f;
        const f32x2 m  = s - 2.0f;
        const f32x2 us = u * s;
        const f32x2 vm = v * m;
        const f32x2 N  = cc * us + vm;
        const f32x2 Dd = us * v;
        f32x2 rD; rD[0] = rcp_fast(Dd[0]); rD[1] = rcp_fast(Dd[1]);
        cc = N * rD;
        f32x2 a2 = cc * TL2E;
        a2[0] = fminf(a2[0], 80.f); a2[1] = fminf(a2[1], 80.f);
        f32x2 Tt; Tt[0] = exp2_fast(a2[0]); Tt[1] = exp2_fast(a2[1]);
        const f32x2 Dh = (eO + 1.0f) * (Tt + 1.0f);
        f32x2 rH; rH[0] = rcp_fast(Dh[0]); rH[1] = rcp_fast(Dh[1]);
        hh01 = (Tt - 1.0f) * rH;

        half2v hv;
        hv[0] = (_Float16)hh01[0];
        hv[1] = (_Float16)hh01[1];
        *(half2v*)(hbase + (t & 1)*2048 + hwoff) = hv;   // slots p0 (T=0), p0+1 (T=1)
        xv = xvn;
        __syncthreads();   // h(t) visible for step t+1
    }

    // ---- fused FC head ----
    float* hsc = (float*)xs;            // reuse: hsc[16][64], real-j indexing
    hsc[l15*64 + w*8 + l4]     = hh01[0];
    hsc[l15*64 + w*8 + 4 + l4] = hh01[1];
    __syncthreads();

    if (tid < 16*FORECAST) {
        const int b = tid / FORECAST;
        const int f = tid % FORECAST;
        float a = fc_b[f];
        #pragma unroll
        for (int jj = 0; jj < 64; ++jj)
            a = fmaf(hsc[b*64 + jj], fc_W[f*64 + jj], a);
        out[(long long)(bb + b)*FORECAST + f] = a;
    }
}

extern "C" void kernel_launch(void* const* d_in, const int* in_sizes, int n_in,
                              void* d_out, int out_size, void* d_ws, size_t ws_size,
                              hipStream_t stream) {
    const float* x    = (const float*)d_in[0];
    const float* W_ih = (const float*)d_in[1];
    const float* W_hh = (const float*)d_in[2];
    const float* b_ih = (const float*)d_in[3];
    const float* b_hh = (const float*)d_in[4];
    const float* fc_W = (const float*)d_in[5];
    const float* fc_b = (const float*)d_in[6];
    float* out = (float*)d_out;

    // 4096 / 16 batches per block = 256 blocks (1 per CU), 8 waves (2/SIMD)
    lstm_mfma_kernel<<<256, 512, 0, stream>>>(x, W_ih, W_hh, b_ih, b_hh, fc_W, fc_b, out);
}